// Round 17
// baseline (274.065 us; speedup 1.0000x reference)
//
#include <hip/hip_runtime.h>

#define NEG_SLOPE 0.2f
#define K1 1024          // coarse buckets: bucket = dst >> 7 (valid for N <= 131072)
#define S1B 512          // edge-chunk blocks

typedef __attribute__((ext_vector_type(8))) short bf16x8;   // MFMA A/B frag
typedef __attribute__((ext_vector_type(4))) float f32x4;    // MFMA C/D frag

// fp32 -> bf16 round-to-nearest-even (no NaN inputs here).
__device__ __forceinline__ unsigned short f2b(float f) {
    unsigned int u = __float_as_uint(f);
    u += 0x7FFFu + ((u >> 16) & 1u);
    return (unsigned short)(u >> 16);
}
__device__ __forceinline__ float blo(unsigned int u) { return __uint_as_float(u << 16); }
__device__ __forceinline__ float bhi(unsigned int u) { return __uint_as_float(u & 0xFFFF0000u); }

// In-block exclusive scan of T[K1] -> sT. 256 threads, 4 elems each.
__device__ __forceinline__ void tofs_scan(const int* __restrict__ T,
                                          int* sT, int* ps, int t)
{
    int base = t * 4;
    int s0 = T[base], s1 = T[base + 1], s2 = T[base + 2], s3 = T[base + 3];
    int tot = s0 + s1 + s2 + s3;
    ps[t] = tot;
    __syncthreads();
    for (int off = 1; off < 256; off <<= 1) {
        int u = (t >= off) ? ps[t - off] : 0;
        __syncthreads();
        ps[t] += u;
        __syncthreads();
    }
    int excl = ps[t] - tot;
    sT[base]     = excl;
    sT[base + 1] = excl + s0;
    sT[base + 2] = excl + s0 + s1;
    sT[base + 3] = excl + s0 + s1 + s2;
    __syncthreads();
}

// CSR pass 1: per-block LOCAL bucket sort, all global writes block-owned.
// Fused tails: layer-1 scores (parallel fold) + W2 pack.
__global__ __launch_bounds__(256) void k_lsort(
    const int* __restrict__ ei, int E, int EN,
    int2* __restrict__ pairs,               // [S1B][K1] (ofs,cnt)
    unsigned int* __restrict__ tmp,         // [EN] block-major, bucket-sorted
    const float* __restrict__ x, const float* __restrict__ W1,
    const float* __restrict__ as1, const float* __restrict__ ad1,
    float* __restrict__ asrc, float* __restrict__ adst,
    const float* __restrict__ W2, unsigned short* __restrict__ W2p,
    int N, int AB)
{
    int b = blockIdx.x;
    int t = threadIdx.x;
    if (b < S1B) {
        __shared__ int hist[K1];
        __shared__ int ofs[K1];
        __shared__ int cur[K1];
        __shared__ int ps[256];
        for (int k = t; k < K1; k += 256) hist[k] = 0;
        __syncthreads();
        int chunk = (EN + S1B - 1) / S1B;
        int lo = b * chunk, hi = min(lo + chunk, EN);
        for (int e = lo + t; e < hi; e += 256) {
            int dst = (e < E) ? ei[E + e] : (e - E);
            atomicAdd(&hist[dst >> 7], 1);
        }
        __syncthreads();
        // exclusive scan of hist[1024] (4 elems/thread)
        int base = t * 4;
        int h0 = hist[base], h1 = hist[base + 1];
        int h2 = hist[base + 2], h3 = hist[base + 3];
        int tot = h0 + h1 + h2 + h3;
        ps[t] = tot;
        __syncthreads();
        for (int off = 1; off < 256; off <<= 1) {
            int u = (t >= off) ? ps[t - off] : 0;
            __syncthreads();
            ps[t] += u;
            __syncthreads();
        }
        int ex = ps[t] - tot;
        ofs[base]     = ex;
        ofs[base + 1] = ex + h0;
        ofs[base + 2] = ex + h0 + h1;
        ofs[base + 3] = ex + h0 + h1 + h2;
        __syncthreads();
        // contiguous row write + cursor init
        for (int k = t; k < K1; k += 256) {
            pairs[(size_t)b * K1 + k] = make_int2(ofs[k], hist[k]);
            cur[k] = ofs[k];
        }
        __syncthreads();
        // pass 2: scatter into the block's OWN contiguous region
        for (int e = lo + t; e < hi; e += 256) {
            int src, dst;
            if (e < E) { src = ei[e]; dst = ei[E + e]; }
            else       { src = dst = e - E; }
            int pos = lo + atomicAdd(&cur[dst >> 7], 1);
            tmp[pos] = ((unsigned int)src << 7) | (unsigned int)(dst & 127);
        }
        return;
    }
    if (b < S1B + AB) {
        // layer-1 scores; W1/att fold parallel: 4 threads per output, shfl-reduce
        __shared__ float s_wa[32], s_wd[32];
        {
            int oid = t >> 2, part = t & 3;     // 64 outputs x 4 partials
            int k = (oid & 31) >> 2, hh = oid & 3;
            const float* av = (oid < 32) ? as1 : ad1;
            float s = 0.f;
            int cc0 = part * 8;
            #pragma unroll
            for (int i = 0; i < 8; i++) {
                float w = W1[k * 128 + hh * 32 + cc0 + i];
                s = fmaf(w, av[hh * 32 + cc0 + i], s);
            }
            s += __shfl_xor(s, 1, 64);
            s += __shfl_xor(s, 2, 64);
            if (part == 0) {
                if (oid < 32) s_wa[oid] = s;
                else          s_wd[oid - 32] = s;
            }
        }
        __syncthreads();
        int g = (b - S1B) * 256 + t;
        int n = g >> 2;
        if (n >= N) return;
        int hh = g & 3;
        const float* xr = x + (size_t)n * 8;
        float sa = 0.f, sd = 0.f;
        #pragma unroll
        for (int k = 0; k < 8; k++) {
            float xv = xr[k];
            sa = fmaf(xv, s_wa[k * 4 + hh], sa);
            sd = fmaf(xv, s_wd[k * 4 + hh], sd);
        }
        asrc[n * 4 + hh] = sa;
        adst[n * 4 + hh] = sd;
        return;
    }
    int w = t >> 6, lane = t & 63;
    int quad = lane >> 4, lanelo = lane & 15;
    int tile_n = b - S1B - AB;                  // 0..7
    size_t base = (((size_t)tile_n * 4 + w) * 64 + lane) * 8;
    #pragma unroll
    for (int j = 0; j < 8; j++) {
        int k = w * 32 + quad * 8 + j;
        int n = tile_n * 16 + lanelo;
        W2p[base + j] = f2b(W2[k * 128 + n]);
    }
}

// CSR pass 2: bucket totals T[k] = sum_b pairs[b][k].cnt.
__global__ __launch_bounds__(256) void k_colsum(
    const int2* __restrict__ pairs, int* __restrict__ T)
{
    __shared__ int part[256];
    int j = blockIdx.x, t = threadIdx.x;
    int kk = t & 15;                            // bucket within group
    int bs = t >> 4;                            // row slice 0..15
    int k = j * 16 + kk;
    int s = 0;
    for (int b = bs; b < S1B; b += 16)
        s += pairs[(size_t)b * K1 + k].y;
    part[t] = s;
    __syncthreads();
    for (int off = 128; off >= 16; off >>= 1) {
        if (t < off) part[t] += part[t + off];
        __syncthreads();
    }
    if (t < 16) T[j * 16 + t] = part[t];
}

// CSR pass 3: per-bucket gather of the 512 block-runs into LDS staging
// (cooperative, 4 lanes/run), then fine 128-bin counting sort.
__global__ __launch_bounds__(256) void k_fine2(
    const int2* __restrict__ pairs, const unsigned int* __restrict__ tmp,
    const int* __restrict__ T,
    int* __restrict__ esrc, int* __restrict__ rowptr, int N, int EN)
{
    __shared__ int sT[K1];
    __shared__ int ps[256];
    __shared__ int rofs[S1B], rcnt[S1B], sofs[S1B];
    __shared__ unsigned int stg[3072];          // max bucket ~1.9K, 30+ sigma
    __shared__ int hist[128], scn[128];
    int k = blockIdx.x, t = threadIdx.x;
    tofs_scan(T, sT, ps, t);
    int lo = sT[k];
    int nbase = k << 7;
    if (k == K1 - 1 && t == 0) rowptr[N] = EN;
    if (nbase >= N) return;                     // empty tail buckets (dst < N)
    int chunk = (EN + S1B - 1) / S1B;

    // per-block run info for this bucket (strided read-only pair loads)
    #pragma unroll
    for (int i = 0; i < 2; i++) {
        int b = t + i * 256;
        int2 pr = pairs[(size_t)b * K1 + k];
        rofs[b] = pr.x;
        rcnt[b] = pr.y;
    }
    __syncthreads();
    // exclusive scan of rcnt[512] (2 elems/thread)
    int c0 = rcnt[2 * t], c1 = rcnt[2 * t + 1];
    int tot = c0 + c1;
    ps[t] = tot;
    __syncthreads();
    for (int off = 1; off < 256; off <<= 1) {
        int u = (t >= off) ? ps[t - off] : 0;
        __syncthreads();
        ps[t] += u;
        __syncthreads();
    }
    int ex = ps[t] - tot;
    sofs[2 * t] = ex;
    sofs[2 * t + 1] = ex + c0;
    __syncthreads();
    int total = sofs[S1B - 1] + rcnt[S1B - 1];
    // cooperative gather: 4 lanes per run, 64 runs per pass, 8 passes
    #pragma unroll
    for (int p = 0; p < 8; p++) {
        int b = p * 64 + (t >> 2);
        int lj = t & 3;
        int n0 = rcnt[b], o = sofs[b];
        const unsigned int* srcp = tmp + (size_t)b * chunk + rofs[b];
        for (int q = lj; q < n0; q += 4)
            stg[o + q] = srcp[q];
    }
    if (t < 128) hist[t] = 0;
    __syncthreads();
    for (int i = t; i < total; i += 256)
        atomicAdd(&hist[stg[i] & 127], 1);
    __syncthreads();
    int v = (t < 128) ? hist[t] : 0;
    if (t < 128) scn[t] = v;
    __syncthreads();
    for (int off = 1; off < 128; off <<= 1) {
        int u = (t >= off && t < 128) ? scn[t - off] : 0;
        __syncthreads();
        if (t < 128) scn[t] += u;
        __syncthreads();
    }
    if (t < 128) {
        int o = scn[t] - v;                     // exclusive
        int dst = nbase + t;
        if (dst < N) rowptr[dst] = lo + o;
        hist[t] = o;                            // reuse as cursor
    }
    __syncthreads();
    for (int i = t; i < total; i += 256) {
        unsigned int e = stg[i];
        int r = atomicAdd(&hist[e & 127], 1);
        esrc[lo + r] = (int)(e >> 7);
    }
}

// FUSED layer-1 aggregation + out1 + layer-2 feature transform.
// DIAGNOSTIC: still launched as two halves (r16) to keep the cutoff low.
__global__ __launch_bounds__(256) void k_l1f2(
    const int* __restrict__ rowptr, const int* __restrict__ esrc,
    const float* __restrict__ x,
    const float* __restrict__ asrc1, const float* __restrict__ adst1,
    const float* __restrict__ W1, const float* __restrict__ bias1,
    const unsigned short* __restrict__ W2p,
    const float* __restrict__ att_src, const float* __restrict__ att_dst,
    unsigned short* __restrict__ h, float* __restrict__ asrc2,
    float* __restrict__ adst2, int N, int n0)
{
    __shared__ float s_y[32][36];               // 32 nodes x 32ch, pad->36
    __shared__ float s_d[32][4];                // denom per (node, head)
    __shared__ uint4 s_tile[512];               // out1 tile, 32 nodes x 256B
    char* s_a = reinterpret_cast<char*>(s_tile);
    int t = threadIdx.x;
    int mbase = n0 + blockIdx.x * 32;

    // ---- phase 0: layer-1 aggregation into LDS ----
    {
        int nl = t >> 3;                        // 0..31
        int node = mbase + nl;
        if (node >= N) node = N - 1;            // clamp (all stores guarded/LDS)
        int l8 = t & 7;
        int eo = l8 & 3;                        // edge offset 0..3
        int dh = (l8 >> 2) << 2;                // x half: 0 or 4
        const float4* a4p = reinterpret_cast<const float4*>(asrc1);
        float4 ad4 = *reinterpret_cast<const float4*>(adst1 + (size_t)node * 4);
        float acc[4][4];                        // [head][chan]
        #pragma unroll
        for (int hh = 0; hh < 4; hh++)
            #pragma unroll
            for (int c = 0; c < 4; c++) acc[hh][c] = 0.f;
        float d4[4] = {0.f, 0.f, 0.f, 0.f};
        int start = rowptr[node], end = rowptr[node + 1];
        int jj = start + eo;
        for (; jj + 4 < end; jj += 8) {
            int s0 = esrc[jj], s1 = esrc[jj + 4];
            float4 a0 = a4p[s0], a1 = a4p[s1];
            float4 x0 = *reinterpret_cast<const float4*>(x + (size_t)s0 * 8 + dh);
            float4 x1 = *reinterpret_cast<const float4*>(x + (size_t)s1 * 8 + dh);
            float w0[4], w1[4];
            float a;
            a = a0.x + ad4.x; a = a > 0.f ? a : NEG_SLOPE * a; w0[0] = __expf(a);
            a = a0.y + ad4.y; a = a > 0.f ? a : NEG_SLOPE * a; w0[1] = __expf(a);
            a = a0.z + ad4.z; a = a > 0.f ? a : NEG_SLOPE * a; w0[2] = __expf(a);
            a = a0.w + ad4.w; a = a > 0.f ? a : NEG_SLOPE * a; w0[3] = __expf(a);
            a = a1.x + ad4.x; a = a > 0.f ? a : NEG_SLOPE * a; w1[0] = __expf(a);
            a = a1.y + ad4.y; a = a > 0.f ? a : NEG_SLOPE * a; w1[1] = __expf(a);
            a = a1.z + ad4.z; a = a > 0.f ? a : NEG_SLOPE * a; w1[2] = __expf(a);
            a = a1.w + ad4.w; a = a > 0.f ? a : NEG_SLOPE * a; w1[3] = __expf(a);
            #pragma unroll
            for (int hh = 0; hh < 4; hh++) {
                acc[hh][0] = fmaf(w0[hh], x0.x, acc[hh][0]);
                acc[hh][1] = fmaf(w0[hh], x0.y, acc[hh][1]);
                acc[hh][2] = fmaf(w0[hh], x0.z, acc[hh][2]);
                acc[hh][3] = fmaf(w0[hh], x0.w, acc[hh][3]);
                acc[hh][0] = fmaf(w1[hh], x1.x, acc[hh][0]);
                acc[hh][1] = fmaf(w1[hh], x1.y, acc[hh][1]);
                acc[hh][2] = fmaf(w1[hh], x1.z, acc[hh][2]);
                acc[hh][3] = fmaf(w1[hh], x1.w, acc[hh][3]);
                d4[hh] += w0[hh] + w1[hh];
            }
        }
        if (jj < end) {
            int s0 = esrc[jj];
            float4 a0 = a4p[s0];
            float4 x0 = *reinterpret_cast<const float4*>(x + (size_t)s0 * 8 + dh);
            float w0[4];
            float a;
            a = a0.x + ad4.x; a = a > 0.f ? a : NEG_SLOPE * a; w0[0] = __expf(a);
            a = a0.y + ad4.y; a = a > 0.f ? a : NEG_SLOPE * a; w0[1] = __expf(a);
            a = a0.z + ad4.z; a = a > 0.f ? a : NEG_SLOPE * a; w0[2] = __expf(a);
            a = a0.w + ad4.w; a = a > 0.f ? a : NEG_SLOPE * a; w0[3] = __expf(a);
            #pragma unroll
            for (int hh = 0; hh < 4; hh++) {
                acc[hh][0] = fmaf(w0[hh], x0.x, acc[hh][0]);
                acc[hh][1] = fmaf(w0[hh], x0.y, acc[hh][1]);
                acc[hh][2] = fmaf(w0[hh], x0.z, acc[hh][2]);
                acc[hh][3] = fmaf(w0[hh], x0.w, acc[hh][3]);
                d4[hh] += w0[hh];
            }
        }
        // reduce over the 4 eo lanes (lane bits 0-1)
        #pragma unroll
        for (int hh = 0; hh < 4; hh++) {
            #pragma unroll
            for (int c = 0; c < 4; c++) {
                acc[hh][c] += __shfl_xor(acc[hh][c], 1, 64);
                acc[hh][c] += __shfl_xor(acc[hh][c], 2, 64);
            }
            d4[hh] += __shfl_xor(d4[hh], 1, 64);
            d4[hh] += __shfl_xor(d4[hh], 2, 64);
        }
        if (eo == 0) {
            #pragma unroll
            for (int hh = 0; hh < 4; hh++) {
                float4 o = {acc[hh][0], acc[hh][1], acc[hh][2], acc[hh][3]};
                *reinterpret_cast<float4*>(&s_y[nl][hh * 8 + dh]) = o;
            }
            if (dh == 0) {
                float4 od = {d4[0], d4[1], d4[2], d4[3]};
                *reinterpret_cast<float4*>(&s_d[nl][0]) = od;
            }
        }
    }
    __syncthreads();

    // ---- phase 1: out1 tile into s_tile (XOR-swizzled) ----
    {
        int nl = t >> 3;                        // 0..31
        int seg = t & 7;                        // 16 channels each
        int head = seg >> 1;
        float inv = 1.f / s_d[nl][head];
        float y8[8];
        #pragma unroll
        for (int k = 0; k < 8; k++) y8[k] = s_y[nl][head * 8 + k];
        int c0 = seg * 16;
        float acc16[16];
        #pragma unroll
        for (int c = 0; c < 16; c++) acc16[c] = 0.f;
        #pragma unroll
        for (int k = 0; k < 8; k++) {
            float yk = y8[k];
            const float4* wr = reinterpret_cast<const float4*>(W1 + k * 128 + c0);
            #pragma unroll
            for (int q = 0; q < 4; q++) {
                float4 wv = wr[q];
                acc16[q * 4 + 0] = fmaf(yk, wv.x, acc16[q * 4 + 0]);
                acc16[q * 4 + 1] = fmaf(yk, wv.y, acc16[q * 4 + 1]);
                acc16[q * 4 + 2] = fmaf(yk, wv.z, acc16[q * 4 + 2]);
                acc16[q * 4 + 3] = fmaf(yk, wv.w, acc16[q * 4 + 3]);
            }
        }
        unsigned int dw[8];
        #pragma unroll
        for (int c = 0; c < 8; c++) {
            float v0 = acc16[2 * c]     * inv + bias1[c0 + 2 * c];
            float v1 = acc16[2 * c + 1] * inv + bias1[c0 + 2 * c + 1];
            v0 = v0 > 0.f ? v0 : 0.f;
            v1 = v1 > 0.f ? v1 : 0.f;
            dw[c] = ((unsigned int)f2b(v1) << 16) | f2b(v0);
        }
        int byte0 = nl * 256 + seg * 32;
        int swz = (nl & 7) << 4;
        *reinterpret_cast<uint4*>(&s_a[byte0 ^ swz]) =
            make_uint4(dw[0], dw[1], dw[2], dw[3]);
        *reinterpret_cast<uint4*>(&s_a[(byte0 + 16) ^ swz]) =
            make_uint4(dw[4], dw[5], dw[6], dw[7]);
    }
    __syncthreads();

    // ---- phase 2: MFMA, A from LDS ----
    int w = t >> 6;
    int lane = t & 63;
    int quad = lane >> 4, lanelo = lane & 15;
    int wcb = w * 32;                           // wave col base == head w * 32

    f32x4 acc[2][2];
    #pragma unroll
    for (int rt = 0; rt < 2; rt++)
        #pragma unroll
        for (int ct = 0; ct < 2; ct++)
            acc[rt][ct] = (f32x4){0.f, 0.f, 0.f, 0.f};

    #pragma unroll
    for (int kc = 0; kc < 4; kc++) {
        bf16x8 a[2], b[2];
        #pragma unroll
        for (int rt = 0; rt < 2; rt++) {
            int nl = rt * 16 + lanelo;
            int byte = nl * 256 + kc * 64 + quad * 16;
            a[rt] = *reinterpret_cast<const bf16x8*>(&s_a[byte ^ ((nl & 7) << 4)]);
        }
        #pragma unroll
        for (int ct = 0; ct < 2; ct++) {
            int tile_n = w * 2 + ct;
            b[ct] = *reinterpret_cast<const bf16x8*>(
                W2p + (((size_t)tile_n * 4 + kc) * 64 + lane) * 8);
        }
        #pragma unroll
        for (int rt = 0; rt < 2; rt++)
            #pragma unroll
            for (int ct = 0; ct < 2; ct++)
                acc[rt][ct] = __builtin_amdgcn_mfma_f32_16x16x32_bf16(
                    a[rt], b[ct], acc[rt][ct], 0, 0, 0);
    }

    // Epilogue. C/D layout: n = lane&15, m = quad*4 + reg.
    float as_[2], ad_[2];
    #pragma unroll
    for (int ct = 0; ct < 2; ct++) {
        int col = wcb + ct * 16 + lanelo;
        as_[ct] = att_src[col];
        ad_[ct] = att_dst[col];
    }
    #pragma unroll
    for (int rt = 0; rt < 2; rt++) {
        #pragma unroll
        for (int reg = 0; reg < 4; reg++) {
            int node = mbase + rt * 16 + quad * 4 + reg;
            bool ok = node < N;
            float v0 = acc[rt][0][reg], v1 = acc[rt][1][reg];
            if (ok) {
                h[(size_t)node * 128 + wcb + lanelo]      = f2b(v0);
                h[(size_t)node * 128 + wcb + 16 + lanelo] = f2b(v1);
            }
            float ps = v0 * as_[0] + v1 * as_[1];
            float pd = v0 * ad_[0] + v1 * ad_[1];
            #pragma unroll
            for (int off = 8; off >= 1; off >>= 1) {
                ps += __shfl_xor(ps, off, 64);
                pd += __shfl_xor(pd, off, 64);
            }
            if (ok && lanelo == 0) {
                asrc2[node * 4 + w] = ps;
                adst2[node * 4 + w] = pd;
            }
        }
    }
}

// Layer-2 aggregation core: 16 lanes/node, 8 ch/lane, 4-wide edge batch.
__device__ __forceinline__ void agg_edge(float w, uint4 u, float acc[8])
{
    acc[0] = fmaf(w, blo(u.x), acc[0]); acc[1] = fmaf(w, bhi(u.x), acc[1]);
    acc[2] = fmaf(w, blo(u.y), acc[2]); acc[3] = fmaf(w, bhi(u.y), acc[3]);
    acc[4] = fmaf(w, blo(u.z), acc[4]); acc[5] = fmaf(w, bhi(u.z), acc[5]);
    acc[6] = fmaf(w, blo(u.w), acc[6]); acc[7] = fmaf(w, bhi(u.w), acc[7]);
}

__device__ __forceinline__ void agg_core16(
    int n, int l4,
    const int* __restrict__ rowptr, const int* __restrict__ esrc,
    const uint4* __restrict__ h /* 16 uint4 per node */,
    const float* __restrict__ asrc, const float* __restrict__ adst,
    float acc[8], float& d)
{
    int head = l4 >> 2;
    float ad = adst[n * 4 + head];
    #pragma unroll
    for (int k = 0; k < 8; k++) acc[k] = 0.f;
    d = 0.f;
    int j = rowptr[n], end = rowptr[n + 1];

    for (; j + 4 <= end; j += 4) {
        int s0 = esrc[j], s1 = esrc[j + 1], s2 = esrc[j + 2], s3 = esrc[j + 3];
        float A0 = asrc[s0 * 4 + head];
        float A1 = asrc[s1 * 4 + head];
        float A2 = asrc[s2 * 4 + head];
        float A3 = asrc[s3 * 4 + head];
        uint4 u0 = h[(size_t)s0 * 16 + l4];
        uint4 u1 = h[(size_t)s1 * 16 + l4];
        uint4 u2 = h[(size_t)s2 * 16 + l4];
        uint4 u3 = h[(size_t)s3 * 16 + l4];
        A0 += ad; A0 = A0 > 0.f ? A0 : NEG_SLOPE * A0; float w0 = __expf(A0);
        A1 += ad; A1 = A1 > 0.f ? A1 : NEG_SLOPE * A1; float w1 = __expf(A1);
        A2 += ad; A2 = A2 > 0.f ? A2 : NEG_SLOPE * A2; float w2 = __expf(A2);
        A3 += ad; A3 = A3 > 0.f ? A3 : NEG_SLOPE * A3; float w3 = __expf(A3);
        agg_edge(w0, u0, acc); d += w0;
        agg_edge(w1, u1, acc); d += w1;
        agg_edge(w2, u2, acc); d += w2;
        agg_edge(w3, u3, acc); d += w3;
    }
    for (; j < end; j++) {
        int src = esrc[j];
        float a = asrc[src * 4 + head] + ad;
        a = a > 0.f ? a : NEG_SLOPE * a;
        float w = __expf(a);
        uint4 u = h[(size_t)src * 16 + l4];
        agg_edge(w, u, acc); d += w;
    }
}

// Layer-2 aggregate + fused final: mean over heads, +bias2, relu, dot W_lin.
// DIAGNOSTIC: node-range [n0,n1) halves (validated r13) to lower the top-5
// cutoff to ~36us so the CSR kernels finally produce counter rows.
__global__ __launch_bounds__(256) void k_agg2(
    const int* __restrict__ rowptr, const int* __restrict__ esrc,
    const uint4* __restrict__ h, const float* __restrict__ asrc,
    const float* __restrict__ adst, const float* __restrict__ bias2,
    const float* __restrict__ Wlin, const float* __restrict__ blin,
    float* __restrict__ out, int n0, int n1)
{
    int gid = blockIdx.x * 256 + threadIdx.x;
    int node = n0 + (gid >> 4);
    if (node >= n1) return;
    int l4 = threadIdx.x & 15;
    float acc[8], d;
    agg_core16(node, l4, rowptr, esrc, h, asrc, adst, acc, d);
    float inv = 1.f / d;
    float v[8];
    #pragma unroll
    for (int k = 0; k < 8; k++) v[k] = acc[k] * inv;
    #pragma unroll
    for (int k = 0; k < 8; k++) {
        v[k] += __shfl_xor(v[k], 4, 64);
        v[k] += __shfl_xor(v[k], 8, 64);
    }
    int cc = (l4 & 3) * 8;
    const float4 b0 = *reinterpret_cast<const float4*>(bias2 + cc);
    const float4 b1 = *reinterpret_cast<const float4*>(bias2 + cc + 4);
    const float4 w0 = *reinterpret_cast<const float4*>(Wlin + cc);
    const float4 w1 = *reinterpret_cast<const float4*>(Wlin + cc + 4);
    float bb[8] = {b0.x, b0.y, b0.z, b0.w, b1.x, b1.y, b1.z, b1.w};
    float ww[8] = {w0.x, w0.y, w0.z, w0.w, w1.x, w1.y, w1.z, w1.w};
    float t = 0.f;
    #pragma unroll
    for (int k = 0; k < 8; k++) {
        float m = 0.25f * v[k] + bb[k];
        float y = m > 0.f ? m : 0.f;
        t = fmaf(y, ww[k], t);
    }
    t += __shfl_xor(t, 1, 64);
    t += __shfl_xor(t, 2, 64);
    if (l4 == 0) out[node] = t + blin[0];
}

extern "C" void kernel_launch(void* const* d_in, const int* in_sizes, int n_in,
                              void* d_out, int out_size, void* d_ws, size_t ws_size,
                              hipStream_t stream)
{
    const float* x   = (const float*)d_in[0];
    const int*   ei  = (const int*)  d_in[1];
    const float* W1  = (const float*)d_in[2];
    const float* as1 = (const float*)d_in[3];
    const float* ad1 = (const float*)d_in[4];
    const float* b1  = (const float*)d_in[5];
    const float* W2  = (const float*)d_in[6];
    const float* as2 = (const float*)d_in[7];
    const float* ad2 = (const float*)d_in[8];
    const float* b2  = (const float*)d_in[9];
    const float* Wl  = (const float*)d_in[10];
    const float* bl  = (const float*)d_in[11];
    float* out = (float*)d_out;

    int N  = in_sizes[0] / 8;
    int E  = in_sizes[1] / 2;
    int EN = E + N;

    float* ws    = (float*)d_ws;
    unsigned short* A = (unsigned short*)ws;    // N*128 bf16: h2
    float* asrc1 = ws + (size_t)N * 64;         // N*4 (layer-1 scores)
    float* adst1 = asrc1 + (size_t)N * 4;       // N*4
    float* asrc2 = adst1 + (size_t)N * 4;       // N*4 (layer-2 scores)
    float* adst2 = asrc2 + (size_t)N * 4;       // N*4
    int* rowptr  = (int*)(adst2 + (size_t)N * 4);// N+1
    int* esrc    = rowptr + (N + 1);            // EN
    int* T       = esrc + EN;                   // K1
    unsigned short* W2p = (unsigned short*)(T + K1);  // 16384 bf16
    uintptr_t pp = (uintptr_t)(W2p + 16384);
    pp = (pp + 7) & ~(uintptr_t)7;
    int2* pairs  = (int2*)pp;                   // [S1B][K1] (4 MB)
    unsigned int* tmp = (unsigned int*)(pairs + (size_t)S1B * K1); // EN u32

    int ab = (N + 63) / 64;                     // att1 blocks (4 lanes/node)
    int halfL = ((N / 2) + 31) & ~31;           // l1f2 split point (32-aligned)
    int nba = halfL / 32;
    int nbb = (N - halfL + 31) / 32;
    int halfA = (N + 1) / 2;                    // agg2 split point
    int nb1 = (halfA + 15) / 16;
    int nb2 = (N - halfA + 15) / 16;

    // Atomic-free CSR build, all global writes block-owned.
    k_lsort<<<S1B + ab + 8, 256, 0, stream>>>(ei, E, EN, pairs, tmp,
                                              x, W1, as1, ad1, asrc1, adst1,
                                              W2, W2p, N, ab);
    k_colsum<<<K1 / 16, 256, 0, stream>>>(pairs, T);
    k_fine2<<<K1, 256, 0, stream>>>(pairs, tmp, T, esrc, rowptr, N, EN);

    // Fused layer-1 aggregation + out1 + layer-2 features/scores (two halves)
    k_l1f2<<<nba, 256, 0, stream>>>(rowptr, esrc, x, asrc1, adst1,
                                    W1, b1, W2p, as2, ad2,
                                    A, asrc2, adst2, N, 0);
    k_l1f2<<<nbb, 256, 0, stream>>>(rowptr, esrc, x, asrc1, adst1,
                                    W1, b1, W2p, as2, ad2,
                                    A, asrc2, adst2, N, halfL);
    // Layer-2 aggregation + fused final head (two halves)
    k_agg2<<<nb1, 256, 0, stream>>>(rowptr, esrc, (const uint4*)A,
                                    asrc2, adst2, b2, Wl, bl, out, 0, halfA);
    k_agg2<<<nb2, 256, 0, stream>>>(rowptr, esrc, (const uint4*)A,
                                    asrc2, adst2, b2, Wl, bl, out, halfA, N);
}

// Round 18
// 254.512 us; speedup vs baseline: 1.0768x; 1.0768x over previous
//
#include <hip/hip_runtime.h>

#define NEG_SLOPE 0.2f
#define K1 1024          // coarse buckets: bucket = dst >> 7 (valid for N <= 131072)
#define S1B 512          // edge-chunk blocks

typedef __attribute__((ext_vector_type(8))) short bf16x8;   // MFMA A/B frag
typedef __attribute__((ext_vector_type(4))) float f32x4;    // MFMA C/D frag

// fp32 -> bf16 round-to-nearest-even (no NaN inputs here).
__device__ __forceinline__ unsigned short f2b(float f) {
    unsigned int u = __float_as_uint(f);
    u += 0x7FFFu + ((u >> 16) & 1u);
    return (unsigned short)(u >> 16);
}
__device__ __forceinline__ float blo(unsigned int u) { return __uint_as_float(u << 16); }
__device__ __forceinline__ float bhi(unsigned int u) { return __uint_as_float(u & 0xFFFF0000u); }

// In-block exclusive scan of T[K1] -> sT. 256 threads, 4 elems each.
__device__ __forceinline__ void tofs_scan(const int* __restrict__ T,
                                          int* sT, int* ps, int t)
{
    int base = t * 4;
    int s0 = T[base], s1 = T[base + 1], s2 = T[base + 2], s3 = T[base + 3];
    int tot = s0 + s1 + s2 + s3;
    ps[t] = tot;
    __syncthreads();
    for (int off = 1; off < 256; off <<= 1) {
        int u = (t >= off) ? ps[t - off] : 0;
        __syncthreads();
        ps[t] += u;
        __syncthreads();
    }
    int excl = ps[t] - tot;
    sT[base]     = excl;
    sT[base + 1] = excl + s0;
    sT[base + 2] = excl + s0 + s1;
    sT[base + 3] = excl + s0 + s1 + s2;
    __syncthreads();
}

// CSR pass 1: per-block LOCAL bucket sort, all global writes block-owned.
// Fused tails: layer-1 scores (parallel fold) + W2 pack.
// (Second ei read in the scatter pass is L1-resident — each block's 13KB
// chunk was just read in the hist pass; no staging needed.)
__global__ __launch_bounds__(256) void k_lsort(
    const int* __restrict__ ei, int E, int EN,
    int2* __restrict__ pairs,               // [S1B][K1] (ofs,cnt)
    unsigned int* __restrict__ tmp,         // [EN] block-major, bucket-sorted
    const float* __restrict__ x, const float* __restrict__ W1,
    const float* __restrict__ as1, const float* __restrict__ ad1,
    float* __restrict__ asrc, float* __restrict__ adst,
    const float* __restrict__ W2, unsigned short* __restrict__ W2p,
    int N, int AB)
{
    int b = blockIdx.x;
    int t = threadIdx.x;
    if (b < S1B) {
        __shared__ int hist[K1];
        __shared__ int ofs[K1];
        __shared__ int cur[K1];
        __shared__ int ps[256];
        for (int k = t; k < K1; k += 256) hist[k] = 0;
        __syncthreads();
        int chunk = (EN + S1B - 1) / S1B;
        int lo = b * chunk, hi = min(lo + chunk, EN);
        for (int e = lo + t; e < hi; e += 256) {
            int dst = (e < E) ? ei[E + e] : (e - E);
            atomicAdd(&hist[dst >> 7], 1);
        }
        __syncthreads();
        // exclusive scan of hist[1024] (4 elems/thread)
        int base = t * 4;
        int h0 = hist[base], h1 = hist[base + 1];
        int h2 = hist[base + 2], h3 = hist[base + 3];
        int tot = h0 + h1 + h2 + h3;
        ps[t] = tot;
        __syncthreads();
        for (int off = 1; off < 256; off <<= 1) {
            int u = (t >= off) ? ps[t - off] : 0;
            __syncthreads();
            ps[t] += u;
            __syncthreads();
        }
        int ex = ps[t] - tot;
        ofs[base]     = ex;
        ofs[base + 1] = ex + h0;
        ofs[base + 2] = ex + h0 + h1;
        ofs[base + 3] = ex + h0 + h1 + h2;
        __syncthreads();
        // contiguous row write + cursor init
        for (int k = t; k < K1; k += 256) {
            pairs[(size_t)b * K1 + k] = make_int2(ofs[k], hist[k]);
            cur[k] = ofs[k];
        }
        __syncthreads();
        // pass 2: scatter into the block's OWN contiguous region
        for (int e = lo + t; e < hi; e += 256) {
            int src, dst;
            if (e < E) { src = ei[e]; dst = ei[E + e]; }
            else       { src = dst = e - E; }
            int pos = lo + atomicAdd(&cur[dst >> 7], 1);
            tmp[pos] = ((unsigned int)src << 7) | (unsigned int)(dst & 127);
        }
        return;
    }
    if (b < S1B + AB) {
        // layer-1 scores; W1/att fold parallel: 4 threads per output, shfl-reduce
        __shared__ float s_wa[32], s_wd[32];
        {
            int oid = t >> 2, part = t & 3;     // 64 outputs x 4 partials
            int k = (oid & 31) >> 2, hh = oid & 3;
            const float* av = (oid < 32) ? as1 : ad1;
            float s = 0.f;
            int cc0 = part * 8;
            #pragma unroll
            for (int i = 0; i < 8; i++) {
                float w = W1[k * 128 + hh * 32 + cc0 + i];
                s = fmaf(w, av[hh * 32 + cc0 + i], s);
            }
            s += __shfl_xor(s, 1, 64);
            s += __shfl_xor(s, 2, 64);
            if (part == 0) {
                if (oid < 32) s_wa[oid] = s;
                else          s_wd[oid - 32] = s;
            }
        }
        __syncthreads();
        int g = (b - S1B) * 256 + t;
        int n = g >> 2;
        if (n >= N) return;
        int hh = g & 3;
        const float* xr = x + (size_t)n * 8;
        float sa = 0.f, sd = 0.f;
        #pragma unroll
        for (int k = 0; k < 8; k++) {
            float xv = xr[k];
            sa = fmaf(xv, s_wa[k * 4 + hh], sa);
            sd = fmaf(xv, s_wd[k * 4 + hh], sd);
        }
        asrc[n * 4 + hh] = sa;
        adst[n * 4 + hh] = sd;
        return;
    }
    int w = t >> 6, lane = t & 63;
    int quad = lane >> 4, lanelo = lane & 15;
    int tile_n = b - S1B - AB;                  // 0..7
    size_t base = (((size_t)tile_n * 4 + w) * 64 + lane) * 8;
    #pragma unroll
    for (int j = 0; j < 8; j++) {
        int k = w * 32 + quad * 8 + j;
        int n = tile_n * 16 + lanelo;
        W2p[base + j] = f2b(W2[k * 128 + n]);
    }
}

// CSR pass 2: bucket totals T[k] = sum_b pairs[b][k].cnt.
__global__ __launch_bounds__(256) void k_colsum(
    const int2* __restrict__ pairs, int* __restrict__ T)
{
    __shared__ int part[256];
    int j = blockIdx.x, t = threadIdx.x;
    int kk = t & 15;                            // bucket within group
    int bs = t >> 4;                            // row slice 0..15
    int k = j * 16 + kk;
    int s = 0;
    for (int b = bs; b < S1B; b += 16)
        s += pairs[(size_t)b * K1 + k].y;
    part[t] = s;
    __syncthreads();
    for (int off = 128; off >= 16; off >>= 1) {
        if (t < off) part[t] += part[t + off];
        __syncthreads();
    }
    if (t < 16) T[j * 16 + t] = part[t];
}

// CSR pass 3: per-bucket gather of the 512 block-runs into LDS staging
// (cooperative, 4 lanes/run), then fine 128-bin counting sort.
__global__ __launch_bounds__(256) void k_fine2(
    const int2* __restrict__ pairs, const unsigned int* __restrict__ tmp,
    const int* __restrict__ T,
    int* __restrict__ esrc, int* __restrict__ rowptr, int N, int EN)
{
    __shared__ int sT[K1];
    __shared__ int ps[256];
    __shared__ int rofs[S1B], rcnt[S1B], sofs[S1B];
    __shared__ unsigned int stg[3072];          // max bucket ~1.9K, 30+ sigma
    __shared__ int hist[128], scn[128];
    int k = blockIdx.x, t = threadIdx.x;
    tofs_scan(T, sT, ps, t);
    int lo = sT[k];
    int nbase = k << 7;
    if (k == K1 - 1 && t == 0) rowptr[N] = EN;
    if (nbase >= N) return;                     // empty tail buckets (dst < N)
    int chunk = (EN + S1B - 1) / S1B;

    // per-block run info for this bucket (strided read-only pair loads)
    #pragma unroll
    for (int i = 0; i < 2; i++) {
        int b = t + i * 256;
        int2 pr = pairs[(size_t)b * K1 + k];
        rofs[b] = pr.x;
        rcnt[b] = pr.y;
    }
    __syncthreads();
    // exclusive scan of rcnt[512] (2 elems/thread)
    int c0 = rcnt[2 * t], c1 = rcnt[2 * t + 1];
    int tot = c0 + c1;
    ps[t] = tot;
    __syncthreads();
    for (int off = 1; off < 256; off <<= 1) {
        int u = (t >= off) ? ps[t - off] : 0;
        __syncthreads();
        ps[t] += u;
        __syncthreads();
    }
    int ex = ps[t] - tot;
    sofs[2 * t] = ex;
    sofs[2 * t + 1] = ex + c0;
    __syncthreads();
    int total = sofs[S1B - 1] + rcnt[S1B - 1];
    // cooperative gather: 4 lanes per run, 64 runs per pass, 8 passes
    #pragma unroll
    for (int p = 0; p < 8; p++) {
        int b = p * 64 + (t >> 2);
        int lj = t & 3;
        int n0 = rcnt[b], o = sofs[b];
        const unsigned int* srcp = tmp + (size_t)b * chunk + rofs[b];
        for (int q = lj; q < n0; q += 4)
            stg[o + q] = srcp[q];
    }
    if (t < 128) hist[t] = 0;
    __syncthreads();
    for (int i = t; i < total; i += 256)
        atomicAdd(&hist[stg[i] & 127], 1);
    __syncthreads();
    int v = (t < 128) ? hist[t] : 0;
    if (t < 128) scn[t] = v;
    __syncthreads();
    for (int off = 1; off < 128; off <<= 1) {
        int u = (t >= off && t < 128) ? scn[t - off] : 0;
        __syncthreads();
        if (t < 128) scn[t] += u;
        __syncthreads();
    }
    if (t < 128) {
        int o = scn[t] - v;                     // exclusive
        int dst = nbase + t;
        if (dst < N) rowptr[dst] = lo + o;
        hist[t] = o;                            // reuse as cursor
    }
    __syncthreads();
    for (int i = t; i < total; i += 256) {
        unsigned int e = stg[i];
        int r = atomicAdd(&hist[e & 127], 1);
        esrc[lo + r] = (int)(e >> 7);
    }
}

// FUSED layer-1 aggregation + out1 + layer-2 feature transform (single launch;
// r16/r17 diagnostic splits reverted). Phase 0 lanes: (x-half, edge-offset).
__global__ __launch_bounds__(256) void k_l1f2(
    const int* __restrict__ rowptr, const int* __restrict__ esrc,
    const float* __restrict__ x,
    const float* __restrict__ asrc1, const float* __restrict__ adst1,
    const float* __restrict__ W1, const float* __restrict__ bias1,
    const unsigned short* __restrict__ W2p,
    const float* __restrict__ att_src, const float* __restrict__ att_dst,
    unsigned short* __restrict__ h, float* __restrict__ asrc2,
    float* __restrict__ adst2, int N)
{
    __shared__ float s_y[32][36];               // 32 nodes x 32ch, pad->36
    __shared__ float s_d[32][4];                // denom per (node, head)
    __shared__ uint4 s_tile[512];               // out1 tile, 32 nodes x 256B
    char* s_a = reinterpret_cast<char*>(s_tile);
    int t = threadIdx.x;
    int mbase = blockIdx.x * 32;

    // ---- phase 0: layer-1 aggregation into LDS ----
    {
        int nl = t >> 3;                        // 0..31
        int node = mbase + nl;
        if (node >= N) node = N - 1;            // clamp (all stores guarded/LDS)
        int l8 = t & 7;
        int eo = l8 & 3;                        // edge offset 0..3
        int dh = (l8 >> 2) << 2;                // x half: 0 or 4
        const float4* a4p = reinterpret_cast<const float4*>(asrc1);
        float4 ad4 = *reinterpret_cast<const float4*>(adst1 + (size_t)node * 4);
        float acc[4][4];                        // [head][chan]
        #pragma unroll
        for (int hh = 0; hh < 4; hh++)
            #pragma unroll
            for (int c = 0; c < 4; c++) acc[hh][c] = 0.f;
        float d4[4] = {0.f, 0.f, 0.f, 0.f};
        int start = rowptr[node], end = rowptr[node + 1];
        int jj = start + eo;
        for (; jj + 4 < end; jj += 8) {
            int s0 = esrc[jj], s1 = esrc[jj + 4];
            float4 a0 = a4p[s0], a1 = a4p[s1];
            float4 x0 = *reinterpret_cast<const float4*>(x + (size_t)s0 * 8 + dh);
            float4 x1 = *reinterpret_cast<const float4*>(x + (size_t)s1 * 8 + dh);
            float w0[4], w1[4];
            float a;
            a = a0.x + ad4.x; a = a > 0.f ? a : NEG_SLOPE * a; w0[0] = __expf(a);
            a = a0.y + ad4.y; a = a > 0.f ? a : NEG_SLOPE * a; w0[1] = __expf(a);
            a = a0.z + ad4.z; a = a > 0.f ? a : NEG_SLOPE * a; w0[2] = __expf(a);
            a = a0.w + ad4.w; a = a > 0.f ? a : NEG_SLOPE * a; w0[3] = __expf(a);
            a = a1.x + ad4.x; a = a > 0.f ? a : NEG_SLOPE * a; w1[0] = __expf(a);
            a = a1.y + ad4.y; a = a > 0.f ? a : NEG_SLOPE * a; w1[1] = __expf(a);
            a = a1.z + ad4.z; a = a > 0.f ? a : NEG_SLOPE * a; w1[2] = __expf(a);
            a = a1.w + ad4.w; a = a > 0.f ? a : NEG_SLOPE * a; w1[3] = __expf(a);
            #pragma unroll
            for (int hh = 0; hh < 4; hh++) {
                acc[hh][0] = fmaf(w0[hh], x0.x, acc[hh][0]);
                acc[hh][1] = fmaf(w0[hh], x0.y, acc[hh][1]);
                acc[hh][2] = fmaf(w0[hh], x0.z, acc[hh][2]);
                acc[hh][3] = fmaf(w0[hh], x0.w, acc[hh][3]);
                acc[hh][0] = fmaf(w1[hh], x1.x, acc[hh][0]);
                acc[hh][1] = fmaf(w1[hh], x1.y, acc[hh][1]);
                acc[hh][2] = fmaf(w1[hh], x1.z, acc[hh][2]);
                acc[hh][3] = fmaf(w1[hh], x1.w, acc[hh][3]);
                d4[hh] += w0[hh] + w1[hh];
            }
        }
        if (jj < end) {
            int s0 = esrc[jj];
            float4 a0 = a4p[s0];
            float4 x0 = *reinterpret_cast<const float4*>(x + (size_t)s0 * 8 + dh);
            float w0[4];
            float a;
            a = a0.x + ad4.x; a = a > 0.f ? a : NEG_SLOPE * a; w0[0] = __expf(a);
            a = a0.y + ad4.y; a = a > 0.f ? a : NEG_SLOPE * a; w0[1] = __expf(a);
            a = a0.z + ad4.z; a = a > 0.f ? a : NEG_SLOPE * a; w0[2] = __expf(a);
            a = a0.w + ad4.w; a = a > 0.f ? a : NEG_SLOPE * a; w0[3] = __expf(a);
            #pragma unroll
            for (int hh = 0; hh < 4; hh++) {
                acc[hh][0] = fmaf(w0[hh], x0.x, acc[hh][0]);
                acc[hh][1] = fmaf(w0[hh], x0.y, acc[hh][1]);
                acc[hh][2] = fmaf(w0[hh], x0.z, acc[hh][2]);
                acc[hh][3] = fmaf(w0[hh], x0.w, acc[hh][3]);
                d4[hh] += w0[hh];
            }
        }
        // reduce over the 4 eo lanes (lane bits 0-1)
        #pragma unroll
        for (int hh = 0; hh < 4; hh++) {
            #pragma unroll
            for (int c = 0; c < 4; c++) {
                acc[hh][c] += __shfl_xor(acc[hh][c], 1, 64);
                acc[hh][c] += __shfl_xor(acc[hh][c], 2, 64);
            }
            d4[hh] += __shfl_xor(d4[hh], 1, 64);
            d4[hh] += __shfl_xor(d4[hh], 2, 64);
        }
        if (eo == 0) {
            #pragma unroll
            for (int hh = 0; hh < 4; hh++) {
                float4 o = {acc[hh][0], acc[hh][1], acc[hh][2], acc[hh][3]};
                *reinterpret_cast<float4*>(&s_y[nl][hh * 8 + dh]) = o;
            }
            if (dh == 0) {
                float4 od = {d4[0], d4[1], d4[2], d4[3]};
                *reinterpret_cast<float4*>(&s_d[nl][0]) = od;
            }
        }
    }
    __syncthreads();

    // ---- phase 1: out1 tile into s_tile (XOR-swizzled) ----
    {
        int nl = t >> 3;                        // 0..31
        int seg = t & 7;                        // 16 channels each
        int head = seg >> 1;
        float inv = 1.f / s_d[nl][head];
        float y8[8];
        #pragma unroll
        for (int k = 0; k < 8; k++) y8[k] = s_y[nl][head * 8 + k];
        int c0 = seg * 16;
        float acc16[16];
        #pragma unroll
        for (int c = 0; c < 16; c++) acc16[c] = 0.f;
        #pragma unroll
        for (int k = 0; k < 8; k++) {
            float yk = y8[k];
            const float4* wr = reinterpret_cast<const float4*>(W1 + k * 128 + c0);
            #pragma unroll
            for (int q = 0; q < 4; q++) {
                float4 wv = wr[q];
                acc16[q * 4 + 0] = fmaf(yk, wv.x, acc16[q * 4 + 0]);
                acc16[q * 4 + 1] = fmaf(yk, wv.y, acc16[q * 4 + 1]);
                acc16[q * 4 + 2] = fmaf(yk, wv.z, acc16[q * 4 + 2]);
                acc16[q * 4 + 3] = fmaf(yk, wv.w, acc16[q * 4 + 3]);
            }
        }
        unsigned int dw[8];
        #pragma unroll
        for (int c = 0; c < 8; c++) {
            float v0 = acc16[2 * c]     * inv + bias1[c0 + 2 * c];
            float v1 = acc16[2 * c + 1] * inv + bias1[c0 + 2 * c + 1];
            v0 = v0 > 0.f ? v0 : 0.f;
            v1 = v1 > 0.f ? v1 : 0.f;
            dw[c] = ((unsigned int)f2b(v1) << 16) | f2b(v0);
        }
        int byte0 = nl * 256 + seg * 32;
        int swz = (nl & 7) << 4;
        *reinterpret_cast<uint4*>(&s_a[byte0 ^ swz]) =
            make_uint4(dw[0], dw[1], dw[2], dw[3]);
        *reinterpret_cast<uint4*>(&s_a[(byte0 + 16) ^ swz]) =
            make_uint4(dw[4], dw[5], dw[6], dw[7]);
    }
    __syncthreads();

    // ---- phase 2: MFMA, A from LDS ----
    int w = t >> 6;
    int lane = t & 63;
    int quad = lane >> 4, lanelo = lane & 15;
    int wcb = w * 32;                           // wave col base == head w * 32

    f32x4 acc[2][2];
    #pragma unroll
    for (int rt = 0; rt < 2; rt++)
        #pragma unroll
        for (int ct = 0; ct < 2; ct++)
            acc[rt][ct] = (f32x4){0.f, 0.f, 0.f, 0.f};

    #pragma unroll
    for (int kc = 0; kc < 4; kc++) {
        bf16x8 a[2], b[2];
        #pragma unroll
        for (int rt = 0; rt < 2; rt++) {
            int nl = rt * 16 + lanelo;
            int byte = nl * 256 + kc * 64 + quad * 16;
            a[rt] = *reinterpret_cast<const bf16x8*>(&s_a[byte ^ ((nl & 7) << 4)]);
        }
        #pragma unroll
        for (int ct = 0; ct < 2; ct++) {
            int tile_n = w * 2 + ct;
            b[ct] = *reinterpret_cast<const bf16x8*>(
                W2p + (((size_t)tile_n * 4 + kc) * 64 + lane) * 8);
        }
        #pragma unroll
        for (int rt = 0; rt < 2; rt++)
            #pragma unroll
            for (int ct = 0; ct < 2; ct++)
                acc[rt][ct] = __builtin_amdgcn_mfma_f32_16x16x32_bf16(
                    a[rt], b[ct], acc[rt][ct], 0, 0, 0);
    }

    // Epilogue. C/D layout: n = lane&15, m = quad*4 + reg.
    float as_[2], ad_[2];
    #pragma unroll
    for (int ct = 0; ct < 2; ct++) {
        int col = wcb + ct * 16 + lanelo;
        as_[ct] = att_src[col];
        ad_[ct] = att_dst[col];
    }
    #pragma unroll
    for (int rt = 0; rt < 2; rt++) {
        #pragma unroll
        for (int reg = 0; reg < 4; reg++) {
            int node = mbase + rt * 16 + quad * 4 + reg;
            bool ok = node < N;
            float v0 = acc[rt][0][reg], v1 = acc[rt][1][reg];
            if (ok) {
                h[(size_t)node * 128 + wcb + lanelo]      = f2b(v0);
                h[(size_t)node * 128 + wcb + 16 + lanelo] = f2b(v1);
            }
            float ps = v0 * as_[0] + v1 * as_[1];
            float pd = v0 * ad_[0] + v1 * ad_[1];
            #pragma unroll
            for (int off = 8; off >= 1; off >>= 1) {
                ps += __shfl_xor(ps, off, 64);
                pd += __shfl_xor(pd, off, 64);
            }
            if (ok && lanelo == 0) {
                asrc2[node * 4 + w] = ps;
                adst2[node * 4 + w] = pd;
            }
        }
    }
}

// Layer-2 aggregation core: 16 lanes/node, 8 ch/lane, 4-wide edge batch.
__device__ __forceinline__ void agg_edge(float w, uint4 u, float acc[8])
{
    acc[0] = fmaf(w, blo(u.x), acc[0]); acc[1] = fmaf(w, bhi(u.x), acc[1]);
    acc[2] = fmaf(w, blo(u.y), acc[2]); acc[3] = fmaf(w, bhi(u.y), acc[3]);
    acc[4] = fmaf(w, blo(u.z), acc[4]); acc[5] = fmaf(w, bhi(u.z), acc[5]);
    acc[6] = fmaf(w, blo(u.w), acc[6]); acc[7] = fmaf(w, bhi(u.w), acc[7]);
}

__device__ __forceinline__ void agg_core16(
    int n, int l4,
    const int* __restrict__ rowptr, const int* __restrict__ esrc,
    const uint4* __restrict__ h /* 16 uint4 per node */,
    const float* __restrict__ asrc, const float* __restrict__ adst,
    float acc[8], float& d)
{
    int head = l4 >> 2;
    float ad = adst[n * 4 + head];
    #pragma unroll
    for (int k = 0; k < 8; k++) acc[k] = 0.f;
    d = 0.f;
    int j = rowptr[n], end = rowptr[n + 1];

    for (; j + 4 <= end; j += 4) {
        int s0 = esrc[j], s1 = esrc[j + 1], s2 = esrc[j + 2], s3 = esrc[j + 3];
        float A0 = asrc[s0 * 4 + head];
        float A1 = asrc[s1 * 4 + head];
        float A2 = asrc[s2 * 4 + head];
        float A3 = asrc[s3 * 4 + head];
        uint4 u0 = h[(size_t)s0 * 16 + l4];
        uint4 u1 = h[(size_t)s1 * 16 + l4];
        uint4 u2 = h[(size_t)s2 * 16 + l4];
        uint4 u3 = h[(size_t)s3 * 16 + l4];
        A0 += ad; A0 = A0 > 0.f ? A0 : NEG_SLOPE * A0; float w0 = __expf(A0);
        A1 += ad; A1 = A1 > 0.f ? A1 : NEG_SLOPE * A1; float w1 = __expf(A1);
        A2 += ad; A2 = A2 > 0.f ? A2 : NEG_SLOPE * A2; float w2 = __expf(A2);
        A3 += ad; A3 = A3 > 0.f ? A3 : NEG_SLOPE * A3; float w3 = __expf(A3);
        agg_edge(w0, u0, acc); d += w0;
        agg_edge(w1, u1, acc); d += w1;
        agg_edge(w2, u2, acc); d += w2;
        agg_edge(w3, u3, acc); d += w3;
    }
    for (; j < end; j++) {
        int src = esrc[j];
        float a = asrc[src * 4 + head] + ad;
        a = a > 0.f ? a : NEG_SLOPE * a;
        float w = __expf(a);
        uint4 u = h[(size_t)src * 16 + l4];
        agg_edge(w, u, acc); d += w;
    }
}

// Layer-2 aggregate + fused final: mean over heads, +bias2, relu, dot W_lin.
// Single launch (r17 diagnostic split reverted — it re-fetched the h-table).
__global__ __launch_bounds__(256) void k_agg2(
    const int* __restrict__ rowptr, const int* __restrict__ esrc,
    const uint4* __restrict__ h, const float* __restrict__ asrc,
    const float* __restrict__ adst, const float* __restrict__ bias2,
    const float* __restrict__ Wlin, const float* __restrict__ blin,
    float* __restrict__ out, int N)
{
    int gid = blockIdx.x * 256 + threadIdx.x;
    int node = gid >> 4;
    if (node >= N) return;
    int l4 = threadIdx.x & 15;
    float acc[8], d;
    agg_core16(node, l4, rowptr, esrc, h, asrc, adst, acc, d);
    float inv = 1.f / d;
    float v[8];
    #pragma unroll
    for (int k = 0; k < 8; k++) v[k] = acc[k] * inv;
    #pragma unroll
    for (int k = 0; k < 8; k++) {
        v[k] += __shfl_xor(v[k], 4, 64);
        v[k] += __shfl_xor(v[k], 8, 64);
    }
    int cc = (l4 & 3) * 8;
    const float4 b0 = *reinterpret_cast<const float4*>(bias2 + cc);
    const float4 b1 = *reinterpret_cast<const float4*>(bias2 + cc + 4);
    const float4 w0 = *reinterpret_cast<const float4*>(Wlin + cc);
    const float4 w1 = *reinterpret_cast<const float4*>(Wlin + cc + 4);
    float bb[8] = {b0.x, b0.y, b0.z, b0.w, b1.x, b1.y, b1.z, b1.w};
    float ww[8] = {w0.x, w0.y, w0.z, w0.w, w1.x, w1.y, w1.z, w1.w};
    float t = 0.f;
    #pragma unroll
    for (int k = 0; k < 8; k++) {
        float m = 0.25f * v[k] + bb[k];
        float y = m > 0.f ? m : 0.f;
        t = fmaf(y, ww[k], t);
    }
    t += __shfl_xor(t, 1, 64);
    t += __shfl_xor(t, 2, 64);
    if (l4 == 0) out[node] = t + blin[0];
}

extern "C" void kernel_launch(void* const* d_in, const int* in_sizes, int n_in,
                              void* d_out, int out_size, void* d_ws, size_t ws_size,
                              hipStream_t stream)
{
    const float* x   = (const float*)d_in[0];
    const int*   ei  = (const int*)  d_in[1];
    const float* W1  = (const float*)d_in[2];
    const float* as1 = (const float*)d_in[3];
    const float* ad1 = (const float*)d_in[4];
    const float* b1  = (const float*)d_in[5];
    const float* W2  = (const float*)d_in[6];
    const float* as2 = (const float*)d_in[7];
    const float* ad2 = (const float*)d_in[8];
    const float* b2  = (const float*)d_in[9];
    const float* Wl  = (const float*)d_in[10];
    const float* bl  = (const float*)d_in[11];
    float* out = (float*)d_out;

    int N  = in_sizes[0] / 8;
    int E  = in_sizes[1] / 2;
    int EN = E + N;

    float* ws    = (float*)d_ws;
    unsigned short* A = (unsigned short*)ws;    // N*128 bf16: h2
    float* asrc1 = ws + (size_t)N * 64;         // N*4 (layer-1 scores)
    float* adst1 = asrc1 + (size_t)N * 4;       // N*4
    float* asrc2 = adst1 + (size_t)N * 4;       // N*4 (layer-2 scores)
    float* adst2 = asrc2 + (size_t)N * 4;       // N*4
    int* rowptr  = (int*)(adst2 + (size_t)N * 4);// N+1
    int* esrc    = rowptr + (N + 1);            // EN
    int* T       = esrc + EN;                   // K1
    unsigned short* W2p = (unsigned short*)(T + K1);  // 16384 bf16
    uintptr_t pp = (uintptr_t)(W2p + 16384);
    pp = (pp + 7) & ~(uintptr_t)7;
    int2* pairs  = (int2*)pp;                   // [S1B][K1] (4 MB)
    unsigned int* tmp = (unsigned int*)(pairs + (size_t)S1B * K1); // EN u32

    int ab = (N + 63) / 64;                     // att1 blocks (4 lanes/node)
    int nb = (N + 15) / 16;                     // agg2: 16 nodes/block

    // Atomic-free CSR build, all global writes block-owned.
    k_lsort<<<S1B + ab + 8, 256, 0, stream>>>(ei, E, EN, pairs, tmp,
                                              x, W1, as1, ad1, asrc1, adst1,
                                              W2, W2p, N, ab);
    k_colsum<<<K1 / 16, 256, 0, stream>>>(pairs, T);
    k_fine2<<<K1, 256, 0, stream>>>(pairs, tmp, T, esrc, rowptr, N, EN);

    // Fused layer-1 aggregation + out1 + layer-2 features/scores
    k_l1f2<<<(N + 31) / 32, 256, 0, stream>>>(rowptr, esrc, x, asrc1, adst1,
                                              W1, b1, W2p, as2, ad2,
                                              A, asrc2, adst2, N);
    // Layer-2 aggregation + fused final head
    k_agg2<<<nb, 256, 0, stream>>>(rowptr, esrc, (const uint4*)A,
                                   asrc2, adst2, b2, Wl, bl, out, N);
}

// Round 20
// 247.784 us; speedup vs baseline: 1.1061x; 1.0272x over previous
//
#include <hip/hip_runtime.h>

#define NEG_SLOPE 0.2f
#define K1 1024          // coarse buckets: bucket = dst >> 7 (valid for N <= 131072)
#define S1B 512          // edge-chunk blocks
#define CAP 2560         // fixed esrc slots per bucket. Only ~782 buckets are
                         // non-empty (dst<N): mean = 128 self + E*128/N = 2176,
                         // sigma ~45 -> CAP gives 8.5 sigma margin (P~1e-14).
                         // (r19 bug: CAP=2048 < mean -> typical-bucket overflow.)

typedef __attribute__((ext_vector_type(8))) short bf16x8;   // MFMA A/B frag
typedef __attribute__((ext_vector_type(4))) float f32x4;    // MFMA C/D frag

// fp32 -> bf16 round-to-nearest-even (no NaN inputs here).
__device__ __forceinline__ unsigned short f2b(float f) {
    unsigned int u = __float_as_uint(f);
    u += 0x7FFFu + ((u >> 16) & 1u);
    return (unsigned short)(u >> 16);
}
__device__ __forceinline__ float blo(unsigned int u) { return __uint_as_float(u << 16); }
__device__ __forceinline__ float bhi(unsigned int u) { return __uint_as_float(u & 0xFFFF0000u); }

// CSR pass 1: per-block LOCAL bucket sort, all global writes block-owned.
// Fused tails: layer-1 scores (parallel fold) + W2 pack.
__global__ __launch_bounds__(256) void k_lsort(
    const int* __restrict__ ei, int E, int EN,
    int2* __restrict__ pairs,               // [S1B][K1] (ofs,cnt)
    unsigned int* __restrict__ tmp,         // [EN] block-major, bucket-sorted
    const float* __restrict__ x, const float* __restrict__ W1,
    const float* __restrict__ as1, const float* __restrict__ ad1,
    float* __restrict__ asrc, float* __restrict__ adst,
    const float* __restrict__ W2, unsigned short* __restrict__ W2p,
    int N, int AB)
{
    int b = blockIdx.x;
    int t = threadIdx.x;
    if (b < S1B) {
        __shared__ int hist[K1];
        __shared__ int ofs[K1];
        __shared__ int cur[K1];
        __shared__ int ps[256];
        for (int k = t; k < K1; k += 256) hist[k] = 0;
        __syncthreads();
        int chunk = (EN + S1B - 1) / S1B;
        int lo = b * chunk, hi = min(lo + chunk, EN);
        for (int e = lo + t; e < hi; e += 256) {
            int dst = (e < E) ? ei[E + e] : (e - E);
            atomicAdd(&hist[dst >> 7], 1);
        }
        __syncthreads();
        // exclusive scan of hist[1024] (4 elems/thread)
        int base = t * 4;
        int h0 = hist[base], h1 = hist[base + 1];
        int h2 = hist[base + 2], h3 = hist[base + 3];
        int tot = h0 + h1 + h2 + h3;
        ps[t] = tot;
        __syncthreads();
        for (int off = 1; off < 256; off <<= 1) {
            int u = (t >= off) ? ps[t - off] : 0;
            __syncthreads();
            ps[t] += u;
            __syncthreads();
        }
        int ex = ps[t] - tot;
        ofs[base]     = ex;
        ofs[base + 1] = ex + h0;
        ofs[base + 2] = ex + h0 + h1;
        ofs[base + 3] = ex + h0 + h1 + h2;
        __syncthreads();
        // contiguous row write + cursor init
        for (int k = t; k < K1; k += 256) {
            pairs[(size_t)b * K1 + k] = make_int2(ofs[k], hist[k]);
            cur[k] = ofs[k];
        }
        __syncthreads();
        // pass 2: scatter into the block's OWN contiguous region
        for (int e = lo + t; e < hi; e += 256) {
            int src, dst;
            if (e < E) { src = ei[e]; dst = ei[E + e]; }
            else       { src = dst = e - E; }
            int pos = lo + atomicAdd(&cur[dst >> 7], 1);
            tmp[pos] = ((unsigned int)src << 7) | (unsigned int)(dst & 127);
        }
        return;
    }
    if (b < S1B + AB) {
        // layer-1 scores; W1/att fold parallel: 4 threads per output, shfl-reduce
        __shared__ float s_wa[32], s_wd[32];
        {
            int oid = t >> 2, part = t & 3;     // 64 outputs x 4 partials
            int k = (oid & 31) >> 2, hh = oid & 3;
            const float* av = (oid < 32) ? as1 : ad1;
            float s = 0.f;
            int cc0 = part * 8;
            #pragma unroll
            for (int i = 0; i < 8; i++) {
                float w = W1[k * 128 + hh * 32 + cc0 + i];
                s = fmaf(w, av[hh * 32 + cc0 + i], s);
            }
            s += __shfl_xor(s, 1, 64);
            s += __shfl_xor(s, 2, 64);
            if (part == 0) {
                if (oid < 32) s_wa[oid] = s;
                else          s_wd[oid - 32] = s;
            }
        }
        __syncthreads();
        int g = (b - S1B) * 256 + t;
        int n = g >> 2;
        if (n >= N) return;
        int hh = g & 3;
        const float* xr = x + (size_t)n * 8;
        float sa = 0.f, sd = 0.f;
        #pragma unroll
        for (int k = 0; k < 8; k++) {
            float xv = xr[k];
            sa = fmaf(xv, s_wa[k * 4 + hh], sa);
            sd = fmaf(xv, s_wd[k * 4 + hh], sd);
        }
        asrc[n * 4 + hh] = sa;
        adst[n * 4 + hh] = sd;
        return;
    }
    int w = t >> 6, lane = t & 63;
    int quad = lane >> 4, lanelo = lane & 15;
    int tile_n = b - S1B - AB;                  // 0..7
    size_t base = (((size_t)tile_n * 4 + w) * 64 + lane) * 8;
    #pragma unroll
    for (int j = 0; j < 8; j++) {
        int k = w * 32 + quad * 8 + j;
        int n = tile_n * 16 + lanelo;
        W2p[base + j] = f2b(W2[k * 128 + n]);
    }
}

// CSR pass 2: bucket k owns esrc[k*CAP .. k*CAP+CAP); no global prefix.
// Per-node extents -> rowse[n] = (start, end).
__global__ __launch_bounds__(256) void k_fine2(
    const int2* __restrict__ pairs, const unsigned int* __restrict__ tmp,
    int* __restrict__ esrc, int2* __restrict__ rowse, int N, int EN)
{
    __shared__ int ps[256];
    __shared__ int rofs[S1B], rcnt[S1B], sofs[S1B];
    __shared__ unsigned int stg[3072];          // max bucket ~2450 (6 sigma)
    __shared__ int hist[128], scn[128];
    int k = blockIdx.x, t = threadIdx.x;
    int nbase = k << 7;
    if (nbase >= N) return;                     // empty tail buckets (dst < N)
    int lo = k * CAP;
    int chunk = (EN + S1B - 1) / S1B;

    // per-block run info for this bucket (strided read-only pair loads)
    #pragma unroll
    for (int i = 0; i < 2; i++) {
        int b = t + i * 256;
        int2 pr = pairs[(size_t)b * K1 + k];
        rofs[b] = pr.x;
        rcnt[b] = pr.y;
    }
    __syncthreads();
    // exclusive scan of rcnt[512] (2 elems/thread)
    int c0 = rcnt[2 * t], c1 = rcnt[2 * t + 1];
    int tot = c0 + c1;
    ps[t] = tot;
    __syncthreads();
    for (int off = 1; off < 256; off <<= 1) {
        int u = (t >= off) ? ps[t - off] : 0;
        __syncthreads();
        ps[t] += u;
        __syncthreads();
    }
    int ex = ps[t] - tot;
    sofs[2 * t] = ex;
    sofs[2 * t + 1] = ex + c0;
    __syncthreads();
    int total = sofs[S1B - 1] + rcnt[S1B - 1];
    // cooperative gather: 4 lanes per run, 64 runs per pass, 8 passes
    #pragma unroll
    for (int p = 0; p < 8; p++) {
        int b = p * 64 + (t >> 2);
        int lj = t & 3;
        int n0 = rcnt[b], o = sofs[b];
        const unsigned int* srcp = tmp + (size_t)b * chunk + rofs[b];
        for (int q = lj; q < n0; q += 4)
            stg[o + q] = srcp[q];
    }
    if (t < 128) hist[t] = 0;
    __syncthreads();
    for (int i = t; i < total; i += 256)
        atomicAdd(&hist[stg[i] & 127], 1);
    __syncthreads();
    int v = (t < 128) ? hist[t] : 0;
    if (t < 128) scn[t] = v;
    __syncthreads();
    for (int off = 1; off < 128; off <<= 1) {
        int u = (t >= off && t < 128) ? scn[t - off] : 0;
        __syncthreads();
        if (t < 128) scn[t] += u;
        __syncthreads();
    }
    if (t < 128) {
        int o = scn[t] - v;                     // exclusive
        int dst = nbase + t;
        if (dst < N) rowse[dst] = make_int2(lo + o, lo + o + v);
        hist[t] = o;                            // reuse as cursor
    }
    __syncthreads();
    for (int i = t; i < total; i += 256) {
        unsigned int e = stg[i];
        int r = atomicAdd(&hist[e & 127], 1);
        esrc[lo + r] = (int)(e >> 7);
    }
}

// FUSED layer-1 aggregation + out1 + layer-2 feature transform.
// Phase 0 lanes: (x-half, edge-offset); each lane computes all 4 heads.
__global__ __launch_bounds__(256) void k_l1f2(
    const int2* __restrict__ rowse, const int* __restrict__ esrc,
    const float* __restrict__ x,
    const float* __restrict__ asrc1, const float* __restrict__ adst1,
    const float* __restrict__ W1, const float* __restrict__ bias1,
    const unsigned short* __restrict__ W2p,
    const float* __restrict__ att_src, const float* __restrict__ att_dst,
    unsigned short* __restrict__ h, float* __restrict__ asrc2,
    float* __restrict__ adst2, int N)
{
    __shared__ float s_y[32][36];               // 32 nodes x 32ch, pad->36
    __shared__ float s_d[32][4];                // denom per (node, head)
    __shared__ uint4 s_tile[512];               // out1 tile, 32 nodes x 256B
    char* s_a = reinterpret_cast<char*>(s_tile);
    int t = threadIdx.x;
    int mbase = blockIdx.x * 32;

    // ---- phase 0: layer-1 aggregation into LDS ----
    {
        int nl = t >> 3;                        // 0..31
        int node = mbase + nl;
        if (node >= N) node = N - 1;            // clamp (all stores guarded/LDS)
        int l8 = t & 7;
        int eo = l8 & 3;                        // edge offset 0..3
        int dh = (l8 >> 2) << 2;                // x half: 0 or 4
        const float4* a4p = reinterpret_cast<const float4*>(asrc1);
        float4 ad4 = *reinterpret_cast<const float4*>(adst1 + (size_t)node * 4);
        float acc[4][4];                        // [head][chan]
        #pragma unroll
        for (int hh = 0; hh < 4; hh++)
            #pragma unroll
            for (int c = 0; c < 4; c++) acc[hh][c] = 0.f;
        float d4[4] = {0.f, 0.f, 0.f, 0.f};
        int2 se = rowse[node];
        int start = se.x, end = se.y;
        int jj = start + eo;
        for (; jj + 4 < end; jj += 8) {
            int s0 = esrc[jj], s1 = esrc[jj + 4];
            float4 a0 = a4p[s0], a1 = a4p[s1];
            float4 x0 = *reinterpret_cast<const float4*>(x + (size_t)s0 * 8 + dh);
            float4 x1 = *reinterpret_cast<const float4*>(x + (size_t)s1 * 8 + dh);
            float w0[4], w1[4];
            float a;
            a = a0.x + ad4.x; a = a > 0.f ? a : NEG_SLOPE * a; w0[0] = __expf(a);
            a = a0.y + ad4.y; a = a > 0.f ? a : NEG_SLOPE * a; w0[1] = __expf(a);
            a = a0.z + ad4.z; a = a > 0.f ? a : NEG_SLOPE * a; w0[2] = __expf(a);
            a = a0.w + ad4.w; a = a > 0.f ? a : NEG_SLOPE * a; w0[3] = __expf(a);
            a = a1.x + ad4.x; a = a > 0.f ? a : NEG_SLOPE * a; w1[0] = __expf(a);
            a = a1.y + ad4.y; a = a > 0.f ? a : NEG_SLOPE * a; w1[1] = __expf(a);
            a = a1.z + ad4.z; a = a > 0.f ? a : NEG_SLOPE * a; w1[2] = __expf(a);
            a = a1.w + ad4.w; a = a > 0.f ? a : NEG_SLOPE * a; w1[3] = __expf(a);
            #pragma unroll
            for (int hh = 0; hh < 4; hh++) {
                acc[hh][0] = fmaf(w0[hh], x0.x, acc[hh][0]);
                acc[hh][1] = fmaf(w0[hh], x0.y, acc[hh][1]);
                acc[hh][2] = fmaf(w0[hh], x0.z, acc[hh][2]);
                acc[hh][3] = fmaf(w0[hh], x0.w, acc[hh][3]);
                acc[hh][0] = fmaf(w1[hh], x1.x, acc[hh][0]);
                acc[hh][1] = fmaf(w1[hh], x1.y, acc[hh][1]);
                acc[hh][2] = fmaf(w1[hh], x1.z, acc[hh][2]);
                acc[hh][3] = fmaf(w1[hh], x1.w, acc[hh][3]);
                d4[hh] += w0[hh] + w1[hh];
            }
        }
        if (jj < end) {
            int s0 = esrc[jj];
            float4 a0 = a4p[s0];
            float4 x0 = *reinterpret_cast<const float4*>(x + (size_t)s0 * 8 + dh);
            float w0[4];
            float a;
            a = a0.x + ad4.x; a = a > 0.f ? a : NEG_SLOPE * a; w0[0] = __expf(a);
            a = a0.y + ad4.y; a = a > 0.f ? a : NEG_SLOPE * a; w0[1] = __expf(a);
            a = a0.z + ad4.z; a = a > 0.f ? a : NEG_SLOPE * a; w0[2] = __expf(a);
            a = a0.w + ad4.w; a = a > 0.f ? a : NEG_SLOPE * a; w0[3] = __expf(a);
            #pragma unroll
            for (int hh = 0; hh < 4; hh++) {
                acc[hh][0] = fmaf(w0[hh], x0.x, acc[hh][0]);
                acc[hh][1] = fmaf(w0[hh], x0.y, acc[hh][1]);
                acc[hh][2] = fmaf(w0[hh], x0.z, acc[hh][2]);
                acc[hh][3] = fmaf(w0[hh], x0.w, acc[hh][3]);
                d4[hh] += w0[hh];
            }
        }
        // reduce over the 4 eo lanes (lane bits 0-1)
        #pragma unroll
        for (int hh = 0; hh < 4; hh++) {
            #pragma unroll
            for (int c = 0; c < 4; c++) {
                acc[hh][c] += __shfl_xor(acc[hh][c], 1, 64);
                acc[hh][c] += __shfl_xor(acc[hh][c], 2, 64);
            }
            d4[hh] += __shfl_xor(d4[hh], 1, 64);
            d4[hh] += __shfl_xor(d4[hh], 2, 64);
        }
        if (eo == 0) {
            #pragma unroll
            for (int hh = 0; hh < 4; hh++) {
                float4 o = {acc[hh][0], acc[hh][1], acc[hh][2], acc[hh][3]};
                *reinterpret_cast<float4*>(&s_y[nl][hh * 8 + dh]) = o;
            }
            if (dh == 0) {
                float4 od = {d4[0], d4[1], d4[2], d4[3]};
                *reinterpret_cast<float4*>(&s_d[nl][0]) = od;
            }
        }
    }
    __syncthreads();

    // ---- phase 1: out1 tile into s_tile (XOR-swizzled) ----
    {
        int nl = t >> 3;                        // 0..31
        int seg = t & 7;                        // 16 channels each
        int head = seg >> 1;
        float inv = 1.f / s_d[nl][head];
        float y8[8];
        #pragma unroll
        for (int k = 0; k < 8; k++) y8[k] = s_y[nl][head * 8 + k];
        int c0 = seg * 16;
        float acc16[16];
        #pragma unroll
        for (int c = 0; c < 16; c++) acc16[c] = 0.f;
        #pragma unroll
        for (int k = 0; k < 8; k++) {
            float yk = y8[k];
            const float4* wr = reinterpret_cast<const float4*>(W1 + k * 128 + c0);
            #pragma unroll
            for (int q = 0; q < 4; q++) {
                float4 wv = wr[q];
                acc16[q * 4 + 0] = fmaf(yk, wv.x, acc16[q * 4 + 0]);
                acc16[q * 4 + 1] = fmaf(yk, wv.y, acc16[q * 4 + 1]);
                acc16[q * 4 + 2] = fmaf(yk, wv.z, acc16[q * 4 + 2]);
                acc16[q * 4 + 3] = fmaf(yk, wv.w, acc16[q * 4 + 3]);
            }
        }
        unsigned int dw[8];
        #pragma unroll
        for (int c = 0; c < 8; c++) {
            float v0 = acc16[2 * c]     * inv + bias1[c0 + 2 * c];
            float v1 = acc16[2 * c + 1] * inv + bias1[c0 + 2 * c + 1];
            v0 = v0 > 0.f ? v0 : 0.f;
            v1 = v1 > 0.f ? v1 : 0.f;
            dw[c] = ((unsigned int)f2b(v1) << 16) | f2b(v0);
        }
        int byte0 = nl * 256 + seg * 32;
        int swz = (nl & 7) << 4;
        *reinterpret_cast<uint4*>(&s_a[byte0 ^ swz]) =
            make_uint4(dw[0], dw[1], dw[2], dw[3]);
        *reinterpret_cast<uint4*>(&s_a[(byte0 + 16) ^ swz]) =
            make_uint4(dw[4], dw[5], dw[6], dw[7]);
    }
    __syncthreads();

    // ---- phase 2: MFMA, A from LDS ----
    int w = t >> 6;
    int lane = t & 63;
    int quad = lane >> 4, lanelo = lane & 15;
    int wcb = w * 32;                           // wave col base == head w * 32

    f32x4 acc[2][2];
    #pragma unroll
    for (int rt = 0; rt < 2; rt++)
        #pragma unroll
        for (int ct = 0; ct < 2; ct++)
            acc[rt][ct] = (f32x4){0.f, 0.f, 0.f, 0.f};

    #pragma unroll
    for (int kc = 0; kc < 4; kc++) {
        bf16x8 a[2], b[2];
        #pragma unroll
        for (int rt = 0; rt < 2; rt++) {
            int nl = rt * 16 + lanelo;
            int byte = nl * 256 + kc * 64 + quad * 16;
            a[rt] = *reinterpret_cast<const bf16x8*>(&s_a[byte ^ ((nl & 7) << 4)]);
        }
        #pragma unroll
        for (int ct = 0; ct < 2; ct++) {
            int tile_n = w * 2 + ct;
            b[ct] = *reinterpret_cast<const bf16x8*>(
                W2p + (((size_t)tile_n * 4 + kc) * 64 + lane) * 8);
        }
        #pragma unroll
        for (int rt = 0; rt < 2; rt++)
            #pragma unroll
            for (int ct = 0; ct < 2; ct++)
                acc[rt][ct] = __builtin_amdgcn_mfma_f32_16x16x32_bf16(
                    a[rt], b[ct], acc[rt][ct], 0, 0, 0);
    }

    // Epilogue. C/D layout: n = lane&15, m = quad*4 + reg.
    float as_[2], ad_[2];
    #pragma unroll
    for (int ct = 0; ct < 2; ct++) {
        int col = wcb + ct * 16 + lanelo;
        as_[ct] = att_src[col];
        ad_[ct] = att_dst[col];
    }
    #pragma unroll
    for (int rt = 0; rt < 2; rt++) {
        #pragma unroll
        for (int reg = 0; reg < 4; reg++) {
            int node = mbase + rt * 16 + quad * 4 + reg;
            bool ok = node < N;
            float v0 = acc[rt][0][reg], v1 = acc[rt][1][reg];
            if (ok) {
                h[(size_t)node * 128 + wcb + lanelo]      = f2b(v0);
                h[(size_t)node * 128 + wcb + 16 + lanelo] = f2b(v1);
            }
            float ps = v0 * as_[0] + v1 * as_[1];
            float pd = v0 * ad_[0] + v1 * ad_[1];
            #pragma unroll
            for (int off = 8; off >= 1; off >>= 1) {
                ps += __shfl_xor(ps, off, 64);
                pd += __shfl_xor(pd, off, 64);
            }
            if (ok && lanelo == 0) {
                asrc2[node * 4 + w] = ps;
                adst2[node * 4 + w] = pd;
            }
        }
    }
}

// Layer-2 aggregation core: 16 lanes/node, 8 ch/lane, 4-wide edge batch.
__device__ __forceinline__ void agg_edge(float w, uint4 u, float acc[8])
{
    acc[0] = fmaf(w, blo(u.x), acc[0]); acc[1] = fmaf(w, bhi(u.x), acc[1]);
    acc[2] = fmaf(w, blo(u.y), acc[2]); acc[3] = fmaf(w, bhi(u.y), acc[3]);
    acc[4] = fmaf(w, blo(u.z), acc[4]); acc[5] = fmaf(w, bhi(u.z), acc[5]);
    acc[6] = fmaf(w, blo(u.w), acc[6]); acc[7] = fmaf(w, bhi(u.w), acc[7]);
}

__device__ __forceinline__ void agg_core16(
    int n, int l4,
    const int2* __restrict__ rowse, const int* __restrict__ esrc,
    const uint4* __restrict__ h /* 16 uint4 per node */,
    const float* __restrict__ asrc, const float* __restrict__ adst,
    float acc[8], float& d)
{
    int head = l4 >> 2;
    float ad = adst[n * 4 + head];
    #pragma unroll
    for (int k = 0; k < 8; k++) acc[k] = 0.f;
    d = 0.f;
    int2 se = rowse[n];
    int j = se.x, end = se.y;

    for (; j + 4 <= end; j += 4) {
        int s0 = esrc[j], s1 = esrc[j + 1], s2 = esrc[j + 2], s3 = esrc[j + 3];
        float A0 = asrc[s0 * 4 + head];
        float A1 = asrc[s1 * 4 + head];
        float A2 = asrc[s2 * 4 + head];
        float A3 = asrc[s3 * 4 + head];
        uint4 u0 = h[(size_t)s0 * 16 + l4];
        uint4 u1 = h[(size_t)s1 * 16 + l4];
        uint4 u2 = h[(size_t)s2 * 16 + l4];
        uint4 u3 = h[(size_t)s3 * 16 + l4];
        A0 += ad; A0 = A0 > 0.f ? A0 : NEG_SLOPE * A0; float w0 = __expf(A0);
        A1 += ad; A1 = A1 > 0.f ? A1 : NEG_SLOPE * A1; float w1 = __expf(A1);
        A2 += ad; A2 = A2 > 0.f ? A2 : NEG_SLOPE * A2; float w2 = __expf(A2);
        A3 += ad; A3 = A3 > 0.f ? A3 : NEG_SLOPE * A3; float w3 = __expf(A3);
        agg_edge(w0, u0, acc); d += w0;
        agg_edge(w1, u1, acc); d += w1;
        agg_edge(w2, u2, acc); d += w2;
        agg_edge(w3, u3, acc); d += w3;
    }
    for (; j < end; j++) {
        int src = esrc[j];
        float a = asrc[src * 4 + head] + ad;
        a = a > 0.f ? a : NEG_SLOPE * a;
        float w = __expf(a);
        uint4 u = h[(size_t)src * 16 + l4];
        agg_edge(w, u, acc); d += w;
    }
}

// Layer-2 aggregate + fused final: mean over heads, +bias2, relu, dot W_lin.
__global__ __launch_bounds__(256) void k_agg2(
    const int2* __restrict__ rowse, const int* __restrict__ esrc,
    const uint4* __restrict__ h, const float* __restrict__ asrc,
    const float* __restrict__ adst, const float* __restrict__ bias2,
    const float* __restrict__ Wlin, const float* __restrict__ blin,
    float* __restrict__ out, int N)
{
    int gid = blockIdx.x * 256 + threadIdx.x;
    int node = gid >> 4;
    if (node >= N) return;
    int l4 = threadIdx.x & 15;
    float acc[8], d;
    agg_core16(node, l4, rowse, esrc, h, asrc, adst, acc, d);
    float inv = 1.f / d;
    float v[8];
    #pragma unroll
    for (int k = 0; k < 8; k++) v[k] = acc[k] * inv;
    #pragma unroll
    for (int k = 0; k < 8; k++) {
        v[k] += __shfl_xor(v[k], 4, 64);
        v[k] += __shfl_xor(v[k], 8, 64);
    }
    int cc = (l4 & 3) * 8;
    const float4 b0 = *reinterpret_cast<const float4*>(bias2 + cc);
    const float4 b1 = *reinterpret_cast<const float4*>(bias2 + cc + 4);
    const float4 w0 = *reinterpret_cast<const float4*>(Wlin + cc);
    const float4 w1 = *reinterpret_cast<const float4*>(Wlin + cc + 4);
    float bb[8] = {b0.x, b0.y, b0.z, b0.w, b1.x, b1.y, b1.z, b1.w};
    float ww[8] = {w0.x, w0.y, w0.z, w0.w, w1.x, w1.y, w1.z, w1.w};
    float t = 0.f;
    #pragma unroll
    for (int k = 0; k < 8; k++) {
        float m = 0.25f * v[k] + bb[k];
        float y = m > 0.f ? m : 0.f;
        t = fmaf(y, ww[k], t);
    }
    t += __shfl_xor(t, 1, 64);
    t += __shfl_xor(t, 2, 64);
    if (l4 == 0) out[node] = t + blin[0];
}

extern "C" void kernel_launch(void* const* d_in, const int* in_sizes, int n_in,
                              void* d_out, int out_size, void* d_ws, size_t ws_size,
                              hipStream_t stream)
{
    const float* x   = (const float*)d_in[0];
    const int*   ei  = (const int*)  d_in[1];
    const float* W1  = (const float*)d_in[2];
    const float* as1 = (const float*)d_in[3];
    const float* ad1 = (const float*)d_in[4];
    const float* b1  = (const float*)d_in[5];
    const float* W2  = (const float*)d_in[6];
    const float* as2 = (const float*)d_in[7];
    const float* ad2 = (const float*)d_in[8];
    const float* b2  = (const float*)d_in[9];
    const float* Wl  = (const float*)d_in[10];
    const float* bl  = (const float*)d_in[11];
    float* out = (float*)d_out;

    int N  = in_sizes[0] / 8;
    int E  = in_sizes[1] / 2;
    int EN = E + N;

    float* ws    = (float*)d_ws;
    unsigned short* A = (unsigned short*)ws;    // N*128 bf16: h2
    float* asrc1 = ws + (size_t)N * 64;         // N*4 (layer-1 scores)
    float* adst1 = asrc1 + (size_t)N * 4;       // N*4
    float* asrc2 = adst1 + (size_t)N * 4;       // N*4 (layer-2 scores)
    float* adst2 = asrc2 + (size_t)N * 4;       // N*4
    int2* rowse  = (int2*)(adst2 + (size_t)N * 4);      // N int2
    int* esrc    = (int*)(rowse + N);           // K1*CAP ints (10.5 MB)
    unsigned short* W2p = (unsigned short*)(esrc + (size_t)K1 * CAP);  // 16384 bf16
    uintptr_t pp = (uintptr_t)(W2p + 16384);
    pp = (pp + 7) & ~(uintptr_t)7;
    int2* pairs  = (int2*)pp;                   // [S1B][K1] (4 MB)
    unsigned int* tmp = (unsigned int*)(pairs + (size_t)S1B * K1); // EN u32

    int ab = (N + 63) / 64;                     // att1 blocks (4 lanes/node)
    int nb = (N + 15) / 16;                     // agg2: 16 nodes/block

    // Atomic-free CSR build, all global writes block-owned; fixed bucket
    // bases eliminate the global prefix (colsum + tofs_scan gone).
    k_lsort<<<S1B + ab + 8, 256, 0, stream>>>(ei, E, EN, pairs, tmp,
                                              x, W1, as1, ad1, asrc1, adst1,
                                              W2, W2p, N, ab);
    k_fine2<<<K1, 256, 0, stream>>>(pairs, tmp, esrc, rowse, N, EN);

    // Fused layer-1 aggregation + out1 + layer-2 features/scores
    k_l1f2<<<(N + 31) / 32, 256, 0, stream>>>(rowse, esrc, x, asrc1, adst1,
                                              W1, b1, W2p, as2, ad2,
                                              A, asrc2, adst2, N);
    // Layer-2 aggregation + fused final head
    k_agg2<<<nb, 256, 0, stream>>>(rowse, esrc, (const uint4*)A,
                                   asrc2, adst2, b2, Wl, bl, out, N);
}